// Round 4
// baseline (400.338 us; speedup 1.0000x reference)
//
#include <hip/hip_runtime.h>
#include <hip/hip_bf16.h>

#define CD 512
#define PD 4096
#define BD 16
#define GKS 8      // Gram split-K factor (K chunks of 512)
#define NTRI 10    // upper-tri 128-blocks of 512x512

typedef __bf16 bf16x8 __attribute__((ext_vector_type(8)));
typedef float f32x4 __attribute__((ext_vector_type(4)));
typedef unsigned short u16x8 __attribute__((ext_vector_type(8)));
typedef unsigned short u16x4 __attribute__((ext_vector_type(4)));

__device__ __forceinline__ unsigned short f2bf(float f) {
  unsigned u = __builtin_bit_cast(unsigned, f);
  u += 0x7FFFu + ((u >> 16) & 1u);  // RNE
  return (unsigned short)(u >> 16);
}
__device__ __forceinline__ float bf2f(unsigned short h) {
  unsigned u = ((unsigned)h) << 16;
  return __builtin_bit_cast(float, u);
}

// ---- W -> hi/lo bf16 [512][512] (Wq, Wk); Wv plain ----
__global__ void convert_w2(const float* __restrict__ Wq, const float* __restrict__ Wk,
                           const float* __restrict__ Wv,
                           unsigned short* __restrict__ Wqh, unsigned short* __restrict__ Wql,
                           unsigned short* __restrict__ Wkh, unsigned short* __restrict__ Wkl,
                           unsigned short* __restrict__ Wvh) {
  int i = blockIdx.x * 256 + threadIdx.x;
  if (i >= CD * CD) return;
  float q = Wq[i]; unsigned short qh = f2bf(q);
  Wqh[i] = qh; Wql[i] = f2bf(q - bf2f(qh));
  float k = Wk[i]; unsigned short kh = f2bf(k);
  Wkh[i] = kh; Wkl[i] = f2bf(k - bf2f(kh));
  Wvh[i] = f2bf(Wv[i]);
}

// ---- x[b][512][4096] fp32 -> xs hi/lo [b][512][4096] bf16
//      + xth [b][4096][512] bf16 (transposed) + per-tile row-sum partials ----
__global__ void convert_x(const float* __restrict__ x, unsigned short* __restrict__ xsh,
                          unsigned short* __restrict__ xsl, unsigned short* __restrict__ xth,
                          float* __restrict__ r_part) {
  __shared__ float tile[64][65];
  int z = blockIdx.z;
  int c0 = blockIdx.y * 64, p0 = blockIdx.x * 64;
  const float* xb = x + (size_t)z * CD * PD;
  int t = threadIdx.x;
  int tr = t >> 4, tc = t & 15;
#pragma unroll
  for (int j = 0; j < 4; ++j) {
    int r = tr + j * 16;
    const float* src = xb + (size_t)(c0 + r) * PD + p0 + tc * 4;
#pragma unroll
    for (int i = 0; i < 4; ++i) tile[r][tc * 4 + i] = src[i];
  }
  __syncthreads();
  // straight split write
#pragma unroll
  for (int j = 0; j < 4; ++j) {
    int r = tr + j * 16;
    u16x4 hv, lv;
#pragma unroll
    for (int i = 0; i < 4; ++i) {
      float v = tile[r][tc * 4 + i];
      unsigned short h = f2bf(v);
      hv[i] = h; lv[i] = f2bf(v - bf2f(h));
    }
    size_t o = (size_t)z * CD * PD + (size_t)(c0 + r) * PD + p0 + tc * 4;
    *reinterpret_cast<u16x4*>(xsh + o) = hv;
    *reinterpret_cast<u16x4*>(xsl + o) = lv;
  }
  // transposed hi write
#pragma unroll
  for (int j = 0; j < 4; ++j) {
    int pr = tr + j * 16;
    u16x4 hv;
#pragma unroll
    for (int i = 0; i < 4; ++i) hv[i] = f2bf(tile[tc * 4 + i][pr]);
    size_t o = (size_t)z * PD * CD + (size_t)(p0 + pr) * CD + c0 + tc * 4;
    *reinterpret_cast<u16x4*>(xth + o) = hv;
  }
  // per-tile row sums (fp32 exact path for rank-1 correction)
  {
    int row = t >> 2, q4 = t & 3;
    float s = 0.f;
#pragma unroll
    for (int i = 0; i < 16; ++i) s += tile[row][q4 * 16 + i];
    s += __shfl_xor(s, 1);
    s += __shfl_xor(s, 2);
    if (q4 == 0)
      r_part[((size_t)z * CD + c0 + row) * 64 + (p0 >> 6)] = s;
  }
}

// ---- r = sum_p x; u' = Wq r + P bq; w = Wk r  (fp32 exact) ----
__global__ void uvw_kernel(const float* __restrict__ r_part, const float* __restrict__ Wq,
                           const float* __restrict__ bq, const float* __restrict__ Wk,
                           float* __restrict__ uw) {
  __shared__ float rl[CD];
  int z = blockIdx.x;
  int c = threadIdx.x;
  const float* rp = r_part + ((size_t)z * CD + c) * 64;
  float s = 0.f;
#pragma unroll
  for (int pb = 0; pb < 64; ++pb) s += rp[pb];
  rl[c] = s;
  __syncthreads();
  float du = 0.f, dw = 0.f;
  const float* wq = Wq + (size_t)c * CD;
  const float* wk = Wk + (size_t)c * CD;
  for (int i = 0; i < CD; ++i) { du += wq[i] * rl[i]; dw += wk[i] * rl[i]; }
  uw[(size_t)z * 2 * CD + c] = du + (float)PD * bq[c];
  uw[(size_t)z * 2 * CD + CD + c] = dw;
}

// ---- generic C[M][N] = sum_k A[M][k]*B[N][k], bf16 MFMA 16x16x32, BK=64,
//      global_load_lds staging with XOR slot swizzle, 1D XCD-chunked grid.
//      TRI: upper-triangle block grid (Gram). SPLITK>1 (TRI only): K arg is the
//      chunk length; compact fp32 partial output [zc][tri][BM][BN]. ----
enum { EPI_F32 = 0, EPI_HILO = 1, EPI_V = 2 };

template <int BM, int BN, int WM, int WN, bool SPLIT, int EPI, bool TRI, int SPLITK = 1>
__global__ __launch_bounds__((BM / WM) * (BN / WN) * 64) void gemm2(
    const unsigned short* __restrict__ Ahi, const unsigned short* __restrict__ Alo,
    const unsigned short* __restrict__ Bhi, const unsigned short* __restrict__ Blo,
    long long sA, long long sB, int ldA, int ldB, int K,
    float* __restrict__ Cf, unsigned short* __restrict__ Chi, unsigned short* __restrict__ Clo,
    long long sC, int ldC, const float* __restrict__ bias, int gx, int gy) {
  constexpr int BK = 64;
  constexpr int WAVES = (BM / WM) * (BN / WN);
  constexpr int NS = SPLIT ? 2 : 1;
  constexpr int MI = WM / 16, NI = WN / 16;
  constexpr int NWN = BN / WN;
  constexpr int CA = BM / 8, CB = BN / 8;  // 1KB chunks per plane
  constexpr int TOT = NS * (CA + CB);
  constexpr bool COMPACT = TRI && (SPLITK > 1);
  __shared__ unsigned short lds[NS * (BM + BN) * BK];

  // bijective XCD-chunk swizzle (m204)
  int nwg = gridDim.x;
  int b = blockIdx.x;
  int q = nwg >> 3, r = nwg & 7, xcd = b & 7, pos = b >> 3;
  int wg = (xcd < r ? xcd * (q + 1) : r * (q + 1) + (xcd - r) * q) + pos;
  int bx, by, z, zc, tpi = 0, kbase = 0;
  if constexpr (TRI) {
    int tri = gy * (gy + 1) / 2;
    int perz = tri * SPLITK;
    z = wg / perz;
    int rem = wg - z * perz;
    int ks = rem / tri;
    tpi = rem - ks * tri;
    int tp = tpi;
    bx = 0;
    while (tp >= gy - bx) { tp -= gy - bx; ++bx; }
    by = bx + tp;
    kbase = ks * K;
    zc = z * SPLITK + ks;
  } else {
    by = wg % gy;
    int t2 = wg / gy;
    bx = t2 % gx;
    z = t2 / gx;
    zc = z;
  }

  const unsigned short* pA0 = Ahi + (size_t)z * sA + (size_t)bx * BM * ldA;
  const unsigned short* pB0 = Bhi + (size_t)z * sB + (size_t)by * BN * ldB;
  const unsigned short* pA1 = SPLIT ? Alo + (size_t)z * sA + (size_t)bx * BM * ldA : pA0;
  const unsigned short* pB1 = SPLIT ? Blo + (size_t)z * sB + (size_t)by * BN * ldB : pB0;

  int tid = threadIdx.x;
  int lane = tid & 63, wid = tid >> 6;
  int wr = wid / NWN, wc = wid % NWN;
  int lr = lane & 15, kh2 = lane >> 4;

  f32x4 acc[MI][NI] = {};

  for (int k0 = kbase; k0 < kbase + K; k0 += BK) {
    // stage: 8 rows x 64 elems per 1KB chunk; lane l -> row +(l>>3), phys slot l&7.
    // element for phys slot s at row r is logical slot s^(r&7) (read applies same XOR)
#pragma unroll
    for (int i = 0; i < TOT / WAVES; ++i) {
      int c = wid + i * WAVES;
      const unsigned short* srcb; int ldX, lofs, rb2;
      if (c < CA)            { srcb = pA0; ldX = ldA; lofs = c * 512;                  rb2 = c * 8; }
      else if (c < NS * CA)  { srcb = pA1; ldX = ldA; lofs = BM * BK + (c - CA) * 512; rb2 = (c - CA) * 8; }
      else if (c < NS * CA + CB) { int cc = c - NS * CA; srcb = pB0; ldX = ldB;
                                   lofs = NS * BM * BK + cc * 512;                     rb2 = cc * 8; }
      else                   { int cc = c - NS * CA - CB; srcb = pB1; ldX = ldB;
                               lofs = NS * BM * BK + BN * BK + cc * 512;               rb2 = cc * 8; }
      int row = rb2 + (lane >> 3);
      const unsigned short* src =
          srcb + (size_t)row * ldX + k0 + (((lane & 7) ^ (row & 7)) << 3);
      __builtin_amdgcn_global_load_lds(
          (const __attribute__((address_space(1))) void*)src,
          (__attribute__((address_space(3))) void*)(lds + lofs), 16, 0, 0);
    }
    __syncthreads();

#pragma unroll
    for (int kk = 0; kk < BK / 32; ++kk) {
      bf16x8 ah[MI], al[MI], bh[NI], bl[NI];
#pragma unroll
      for (int m = 0; m < MI; ++m) {
        int row = wr * WM + m * 16 + lr;
        int so = ((((kk << 2) | kh2) ^ (row & 7)) << 3);
        ah[m] = *reinterpret_cast<const bf16x8*>(&lds[row * BK + so]);
        if constexpr (SPLIT)
          al[m] = *reinterpret_cast<const bf16x8*>(&lds[BM * BK + row * BK + so]);
      }
#pragma unroll
      for (int n = 0; n < NI; ++n) {
        int row = wc * WN + n * 16 + lr;
        int so = ((((kk << 2) | kh2) ^ (row & 7)) << 3);
        bh[n] = *reinterpret_cast<const bf16x8*>(&lds[NS * BM * BK + row * BK + so]);
        if constexpr (SPLIT)
          bl[n] = *reinterpret_cast<const bf16x8*>(&lds[NS * BM * BK + BN * BK + row * BK + so]);
      }
#pragma unroll
      for (int m = 0; m < MI; ++m)
#pragma unroll
        for (int n = 0; n < NI; ++n) {
          acc[m][n] = __builtin_amdgcn_mfma_f32_16x16x32_bf16(ah[m], bh[n], acc[m][n], 0, 0, 0);
          if constexpr (SPLIT) {
            acc[m][n] = __builtin_amdgcn_mfma_f32_16x16x32_bf16(ah[m], bl[n], acc[m][n], 0, 0, 0);
            acc[m][n] = __builtin_amdgcn_mfma_f32_16x16x32_bf16(al[m], bh[n], acc[m][n], 0, 0, 0);
          }
        }
    }
    __syncthreads();
  }

  // epilogue: C/D layout col = lane&15, row = (lane>>4)*4 + reg
  int lg = lane >> 4;
#pragma unroll
  for (int m = 0; m < MI; ++m)
#pragma unroll
    for (int n = 0; n < NI; ++n) {
      int lcol = wc * WN + n * 16 + lr;
      float bcol = (EPI == EPI_V) ? bias[by * BN + lcol] : 0.f;
#pragma unroll
      for (int r4 = 0; r4 < 4; ++r4) {
        int lrow = wr * WM + m * 16 + lg * 4 + r4;
        float v = acc[m][n][r4];
        if constexpr (COMPACT) {
          size_t idx = (size_t)zc * sC + (size_t)tpi * (BM * BN) + (size_t)lrow * BN + lcol;
          Cf[idx] = v;
        } else {
          size_t idx = (size_t)zc * sC + (size_t)(bx * BM + lrow) * ldC + (by * BN + lcol);
          if constexpr (EPI == EPI_F32) {
            Cf[idx] = v;
          } else if constexpr (EPI == EPI_HILO) {
            unsigned short h = f2bf(v);
            Chi[idx] = h;
            Clo[idx] = f2bf(v - bf2f(h));
          } else {
            Chi[idx] = f2bf(v + bcol);
          }
        }
      }
    }
}

// ---- reduce Gram split-K partials + hi/lo split; upper 128-blocks of 512x512 ----
template <int KS>
__global__ void gram_reduce(const float* __restrict__ Gp,
                            unsigned short* __restrict__ Ghi, unsigned short* __restrict__ Glo) {
  int z = blockIdx.y;
  int tp = blockIdx.x;  // 0..NTRI-1
  int b2 = tp, bx = 0;
  while (b2 >= 4 - bx) { b2 -= 4 - bx; ++bx; }
  int by = bx + b2;
  int t = threadIdx.x;
  const float* base = Gp + ((size_t)z * KS * NTRI + tp) * (128 * 128);
  size_t gb = (size_t)z * CD * CD;
#pragma unroll
  for (int it = 0; it < 16; ++it) {
    int lrow = it * 8 + (t >> 5);
    int lc = (t & 31) * 4;
    f32x4 s = *reinterpret_cast<const f32x4*>(base + (size_t)lrow * 128 + lc);
#pragma unroll
    for (int ks = 1; ks < KS; ++ks)
      s += *reinterpret_cast<const f32x4*>(base + (size_t)ks * NTRI * 128 * 128 +
                                           (size_t)lrow * 128 + lc);
    u16x4 h, l;
#pragma unroll
    for (int i = 0; i < 4; ++i) {
      unsigned short hh = f2bf(s[i]);
      h[i] = hh; l[i] = f2bf(s[i] - bf2f(hh));
    }
    size_t o = gb + (size_t)(bx * 128 + lrow) * CD + by * 128 + lc;
    *reinterpret_cast<u16x4*>(Ghi + o) = h;
    *reinterpret_cast<u16x4*>(Glo + o) = l;
  }
}

// ---- mirror lower triangle of G from computed upper (128-block pairs bx<by) ----
__global__ void mirror_g(unsigned short* __restrict__ Ghi, unsigned short* __restrict__ Glo) {
  __shared__ unsigned short shh[64][72], shl[64][72];
  int z = blockIdx.y;
  int pidx = blockIdx.x >> 2, sub = blockIdx.x & 3;
  int bx = 0, tp = pidx;
  while (tp >= 3 - bx) { tp -= 3 - bx; ++bx; }
  int by = bx + 1 + tp;
  int ti = bx * 2 + (sub & 1), tj = by * 2 + (sub >> 1);
  int t = threadIdx.x;
  int rr = t >> 2, cg = (t & 3) * 16;
  size_t gbase = (size_t)z * CD * CD;
  size_t so = gbase + (size_t)(ti * 64 + rr) * CD + tj * 64 + cg;
  *reinterpret_cast<u16x8*>(&shh[rr][cg]) = *reinterpret_cast<const u16x8*>(Ghi + so);
  *reinterpret_cast<u16x8*>(&shh[rr][cg + 8]) = *reinterpret_cast<const u16x8*>(Ghi + so + 8);
  *reinterpret_cast<u16x8*>(&shl[rr][cg]) = *reinterpret_cast<const u16x8*>(Glo + so);
  *reinterpret_cast<u16x8*>(&shl[rr][cg + 8]) = *reinterpret_cast<const u16x8*>(Glo + so + 8);
  __syncthreads();
  u16x8 oh, ol;
  size_t dst = gbase + (size_t)(tj * 64 + rr) * CD + ti * 64 + cg;
#pragma unroll
  for (int half = 0; half < 2; ++half) {
#pragma unroll
    for (int i = 0; i < 8; ++i) {
      oh[i] = shh[cg + half * 8 + i][rr];
      ol[i] = shl[cg + half * 8 + i][rr];
    }
    *reinterpret_cast<u16x8*>(Ghi + dst + half * 8) = oh;
    *reinterpret_cast<u16x8*>(Glo + dst + half * 8) = ol;
  }
}

// ---- row softmax with rank-1 logit correction:
//      e[c][d] = E[c][d] + u'[c]*bk[d] + bq[c]*w[d]  ----
__global__ void softmax_rows(const float* __restrict__ E, unsigned short* __restrict__ attn,
                             const float* __restrict__ bq, const float* __restrict__ bk,
                             const float* __restrict__ uw) {
  int lane = threadIdx.x & 63, wid = threadIdx.x >> 6;
  size_t row = (size_t)blockIdx.x * 4 + wid;
  int z = (int)(row >> 9), c = (int)(row & 511);
  float uc = uw[(size_t)z * 2 * CD + c];
  float bqc = bq[c];
  const float* wp = uw + (size_t)z * 2 * CD + CD;
  const float* e = E + row * CD;
  int d0 = lane * 8;
  const float4* ep = reinterpret_cast<const float4*>(e + d0);
  float4 a = ep[0], b4 = ep[1];
  float4 k0 = *reinterpret_cast<const float4*>(bk + d0);
  float4 k1 = *reinterpret_cast<const float4*>(bk + d0 + 4);
  float4 w0 = *reinterpret_cast<const float4*>(wp + d0);
  float4 w1 = *reinterpret_cast<const float4*>(wp + d0 + 4);
  float v[8] = {a.x + uc * k0.x + bqc * w0.x, a.y + uc * k0.y + bqc * w0.y,
                a.z + uc * k0.z + bqc * w0.z, a.w + uc * k0.w + bqc * w0.w,
                b4.x + uc * k1.x + bqc * w1.x, b4.y + uc * k1.y + bqc * w1.y,
                b4.z + uc * k1.z + bqc * w1.z, b4.w + uc * k1.w + bqc * w1.w};
  float m = v[0];
#pragma unroll
  for (int i = 1; i < 8; ++i) m = fmaxf(m, v[i]);
  for (int o = 32; o > 0; o >>= 1) m = fmaxf(m, __shfl_xor(m, o));
  float s = 0.f;
#pragma unroll
  for (int i = 0; i < 8; ++i) { v[i] = __expf(v[i] - m); s += v[i]; }
  for (int o = 32; o > 0; o >>= 1) s += __shfl_xor(s, o);
  float rinv = 1.0f / s;
  u16x4 h0, h1;
#pragma unroll
  for (int i = 0; i < 4; ++i) { h0[i] = f2bf(v[i] * rinv); h1[i] = f2bf(v[4 + i] * rinv); }
  unsigned short* op = attn + row * CD + d0;
  *reinterpret_cast<u16x4*>(op) = h0;
  *reinterpret_cast<u16x4*>(op + 4) = h1;
}

extern "C" void kernel_launch(void* const* d_in, const int* in_sizes, int n_in,
                              void* d_out, int out_size, void* d_ws, size_t ws_size,
                              hipStream_t stream) {
  (void)in_sizes; (void)n_in; (void)out_size;
  const float* x  = (const float*)d_in[0];
  const float* Wq = (const float*)d_in[1];
  const float* bq = (const float*)d_in[2];
  const float* Wk = (const float*)d_in[3];
  const float* bk = (const float*)d_in[4];
  const float* Wv = (const float*)d_in[5];
  const float* bv = (const float*)d_in[6];
  float* out = (float*)d_out;

  char* base = (char*)d_ws;
  size_t off = 0;
  auto carve = [&](size_t bytes) -> char* {
    char* p = base + off;
    off += (bytes + 255) & ~(size_t)255;
    return p;
  };
  const size_t WB = (size_t)CD * CD * 2;
  unsigned short* Wqh = (unsigned short*)carve(WB);
  unsigned short* Wql = (unsigned short*)carve(WB);
  unsigned short* Wkh = (unsigned short*)carve(WB);
  unsigned short* Wkl = (unsigned short*)carve(WB);
  unsigned short* Wvh = (unsigned short*)carve(WB);

  const size_t CP = (size_t)CD * PD;
  const size_t GG = (size_t)CD * CD;
  const size_t EE = (size_t)CD * CD;
  // per-batch: xsh,xsl,xth (3*CP*2) + Ghi,Glo,Thi,Tlo (4*GG*2) + r_part + uw
  //            + E (EE*4) + att (EE*2) + vT (CP*2)
  const size_t per_batch = 3 * CP * 2 + 4 * GG * 2 + (size_t)CD * 64 * 4 + 2 * CD * 4 +
                           EE * 4 + EE * 2 + CP * 2 + 4096;
  size_t rem = (ws_size > off + 4096) ? (ws_size - off - 4096) : 0;
  int nb = (int)(rem / per_batch);
  if (nb < 1) nb = 1;
  if (nb > BD) nb = BD;

  unsigned short* xsh = (unsigned short*)carve((size_t)nb * CP * 2);
  unsigned short* xsl = (unsigned short*)carve((size_t)nb * CP * 2);
  unsigned short* xth = (unsigned short*)carve((size_t)nb * CP * 2);
  unsigned short* Ghi = (unsigned short*)carve((size_t)nb * GG * 2);
  unsigned short* Glo = (unsigned short*)carve((size_t)nb * GG * 2);
  unsigned short* Thi = (unsigned short*)carve((size_t)nb * GG * 2);
  unsigned short* Tlo = (unsigned short*)carve((size_t)nb * GG * 2);
  float*          r_part = (float*)carve((size_t)nb * CD * 64 * 4);
  float*          uw  = (float*)carve((size_t)nb * 2 * CD * 4);
  float*          E   = (float*)carve((size_t)nb * EE * 4);
  unsigned short* att = (unsigned short*)carve((size_t)nb * EE * 2);
  unsigned short* vT  = (unsigned short*)carve((size_t)nb * CP * 2);

  // Gram split-K partials alias the E/att/vT region (all written after gram_reduce):
  // need nb*GKS*NTRI*128*128*4 = nb*5.24MB <= nb*(EE*4 + EE*2 + CP*2) = nb*5.76MB
  float* Gpart = E;

  convert_w2<<<dim3((CD * CD + 255) / 256), 256, 0, stream>>>(
      Wq, Wk, Wv, Wqh, Wql, Wkh, Wkl, Wvh);

  for (int b0 = 0; b0 < BD; b0 += nb) {
    int cb = (BD - b0 < nb) ? (BD - b0) : nb;

    convert_x<<<dim3(PD / 64, CD / 64, cb), 256, 0, stream>>>(
        x + (size_t)b0 * CP, xsh, xsl, xth, r_part);

    uvw_kernel<<<dim3(cb), 512, 0, stream>>>(r_part, Wq, bq, Wk, uw);

    // G partials = X X^T (upper triangle 128-blocks, split-K), fp32 compact out
    gemm2<128, 128, 64, 32, true, EPI_F32, true, GKS><<<NTRI * GKS * cb, 512, 0, stream>>>(
        xsh, xsl, xsh, xsl, (long long)CP, (long long)CP, PD, PD, PD / GKS,
        Gpart, nullptr, nullptr, (long long)NTRI * 128 * 128, 128, nullptr, 4, 4);

    gram_reduce<GKS><<<dim3(NTRI, cb), 256, 0, stream>>>(Gpart, Ghi, Glo);

    mirror_g<<<dim3(24, cb), 256, 0, stream>>>(Ghi, Glo);

    // T = Wq * G^T (G symmetric), split, hi/lo out [512][512]
    gemm2<64, 64, 32, 32, true, EPI_HILO, false><<<8 * 8 * cb, 256, 0, stream>>>(
        Wqh, Wql, Ghi, Glo, 0, (long long)GG, CD, CD, CD,
        nullptr, Thi, Tlo, (long long)GG, CD, nullptr, 8, 8);

    // E = T * Wk^T, split, fp32 out [512][512]
    gemm2<64, 64, 32, 32, true, EPI_F32, false><<<8 * 8 * cb, 256, 0, stream>>>(
        Thi, Tlo, Wkh, Wkl, (long long)GG, 0, CD, CD, CD,
        E, nullptr, nullptr, (long long)EE, CD, nullptr, 8, 8);

    softmax_rows<<<dim3(cb * CD / 4), 256, 0, stream>>>(E, att, bq, bk, uw);

    // vT[p][o] = xth * Wv^T + bv  [4096][512]
    gemm2<128, 128, 64, 64, false, EPI_V, false><<<32 * 4 * cb, 256, 0, stream>>>(
        xth, nullptr, Wvh, nullptr, (long long)CP, 0, CD, CD, CD,
        nullptr, vT, nullptr, (long long)CP, CD, bv, 32, 4);

    // out = attn * vT^T  [512][4096] fp32
    gemm2<128, 128, 64, 64, false, EPI_F32, false><<<4 * 32 * cb, 256, 0, stream>>>(
        att, nullptr, vT, nullptr, (long long)EE, (long long)CP, CD, CD, CD,
        out + (size_t)b0 * CP, nullptr, nullptr, (long long)CP, PD, nullptr, 4, 32);
  }
}

// Round 5
// 354.003 us; speedup vs baseline: 1.1309x; 1.1309x over previous
//
#include <hip/hip_runtime.h>
#include <hip/hip_bf16.h>

#define CD 512
#define PD 4096
#define BD 16
#define GKS 8      // Gram split-K factor (K chunks of 512)
#define NTRI 10    // upper-tri 128-blocks of 512x512

typedef __bf16 bf16x8 __attribute__((ext_vector_type(8)));
typedef float f32x4 __attribute__((ext_vector_type(4)));
typedef unsigned short u16x8 __attribute__((ext_vector_type(8)));
typedef unsigned short u16x4 __attribute__((ext_vector_type(4)));

__device__ __forceinline__ unsigned short f2bf(float f) {
  unsigned u = __builtin_bit_cast(unsigned, f);
  u += 0x7FFFu + ((u >> 16) & 1u);  // RNE
  return (unsigned short)(u >> 16);
}
__device__ __forceinline__ float bf2f(unsigned short h) {
  unsigned u = ((unsigned)h) << 16;
  return __builtin_bit_cast(float, u);
}

// ---- W -> hi/lo bf16 [512][512] (Wq, Wk); Wv plain ----
__global__ void convert_w2(const float* __restrict__ Wq, const float* __restrict__ Wk,
                           const float* __restrict__ Wv,
                           unsigned short* __restrict__ Wqh, unsigned short* __restrict__ Wql,
                           unsigned short* __restrict__ Wkh, unsigned short* __restrict__ Wkl,
                           unsigned short* __restrict__ Wvh) {
  int i = blockIdx.x * 256 + threadIdx.x;
  if (i >= CD * CD) return;
  float q = Wq[i]; unsigned short qh = f2bf(q);
  Wqh[i] = qh; Wql[i] = f2bf(q - bf2f(qh));
  float k = Wk[i]; unsigned short kh = f2bf(k);
  Wkh[i] = kh; Wkl[i] = f2bf(k - bf2f(kh));
  Wvh[i] = f2bf(Wv[i]);
}

// ---- x[b][512][4096] fp32 -> xs hi/lo bf16 + xth [b][4096][512] bf16
//      + per-tile row-sum partials (computed during load, shfl-reduced) ----
__global__ void convert_x(const float* __restrict__ x, unsigned short* __restrict__ xsh,
                          unsigned short* __restrict__ xsl, unsigned short* __restrict__ xth,
                          float* __restrict__ r_part) {
  __shared__ float tile[64][65];
  int z = blockIdx.z;
  int c0 = blockIdx.y * 64, p0 = blockIdx.x * 64;
  const float* xb = x + (size_t)z * CD * PD;
  int t = threadIdx.x;
  int tr = t >> 4, tc = t & 15;
  float psum[4];
#pragma unroll
  for (int j = 0; j < 4; ++j) {
    int r = tr + j * 16;
    const float* src = xb + (size_t)(c0 + r) * PD + p0 + tc * 4;
    float s = 0.f;
#pragma unroll
    for (int i = 0; i < 4; ++i) {
      float v = src[i];
      tile[r][tc * 4 + i] = v;
      s += v;
    }
    psum[j] = s;
  }
  // 16-lane row reduce (threads sharing a row are consecutive lanes)
#pragma unroll
  for (int j = 0; j < 4; ++j) {
    float s = psum[j];
    s += __shfl_xor(s, 1);
    s += __shfl_xor(s, 2);
    s += __shfl_xor(s, 4);
    s += __shfl_xor(s, 8);
    if (tc == 0)
      r_part[((size_t)z * CD + c0 + tr + j * 16) * 64 + (p0 >> 6)] = s;
  }
  __syncthreads();
  // straight split write
#pragma unroll
  for (int j = 0; j < 4; ++j) {
    int r = tr + j * 16;
    u16x4 hv, lv;
#pragma unroll
    for (int i = 0; i < 4; ++i) {
      float v = tile[r][tc * 4 + i];
      unsigned short h = f2bf(v);
      hv[i] = h; lv[i] = f2bf(v - bf2f(h));
    }
    size_t o = (size_t)z * CD * PD + (size_t)(c0 + r) * PD + p0 + tc * 4;
    *reinterpret_cast<u16x4*>(xsh + o) = hv;
    *reinterpret_cast<u16x4*>(xsl + o) = lv;
  }
  // transposed hi write
#pragma unroll
  for (int j = 0; j < 4; ++j) {
    int pr = tr + j * 16;
    u16x4 hv;
#pragma unroll
    for (int i = 0; i < 4; ++i) hv[i] = f2bf(tile[tc * 4 + i][pr]);
    size_t o = (size_t)z * PD * CD + (size_t)(p0 + pr) * CD + c0 + tc * 4;
    *reinterpret_cast<u16x4*>(xth + o) = hv;
  }
}

// ---- r = sum_p x; u' = Wq r + P bq; w = Wk r  (fp32, coalesced wave-per-row) ----
__global__ void uvw_kernel(const float* __restrict__ r_part, const float* __restrict__ Wq,
                           const float* __restrict__ bq, const float* __restrict__ Wk,
                           float* __restrict__ uw) {
  __shared__ float rl[CD];
  int z = blockIdx.x, rg = blockIdx.y;
  int t = threadIdx.x;
  // phase 1: reduce r_part -> rl (contiguous 256B per thread)
  for (int c = t; c < CD; c += 256) {
    const float* rp = r_part + ((size_t)z * CD + c) * 64;
    f32x4 s4 = *reinterpret_cast<const f32x4*>(rp);
#pragma unroll
    for (int pb = 4; pb < 64; pb += 4) s4 += *reinterpret_cast<const f32x4*>(rp + pb);
    rl[c] = s4[0] + s4[1] + s4[2] + s4[3];
  }
  __syncthreads();
  // phase 2: wave-per-row dot products, lanes along i (coalesced)
  int lane = t & 63, w = t >> 6;
#pragma unroll
  for (int rr = 0; rr < 16; ++rr) {
    int c = rg * 64 + w * 16 + rr;
    const float* wq = Wq + (size_t)c * CD;
    const float* wk = Wk + (size_t)c * CD;
    float du = 0.f, dw = 0.f;
#pragma unroll
    for (int j = 0; j < 8; ++j) {
      float rv = rl[lane + 64 * j];
      du += wq[lane + 64 * j] * rv;
      dw += wk[lane + 64 * j] * rv;
    }
#pragma unroll
    for (int o = 32; o > 0; o >>= 1) {
      du += __shfl_xor(du, o);
      dw += __shfl_xor(dw, o);
    }
    if (lane == 0) {
      uw[(size_t)z * 2 * CD + c] = du + (float)PD * bq[c];
      uw[(size_t)z * 2 * CD + CD + c] = dw;
    }
  }
}

// ---- generic C[M][N] = sum_k A[M][k]*B[N][k], bf16 MFMA 16x16x32, BK=64,
//      global_load_lds staging with XOR slot swizzle, 1D XCD-chunked grid.
//      TRI: upper-triangle block grid (Gram). SPLITK>1 (TRI only): K arg is the
//      chunk length; compact fp32 partial output [zc][tri][BM][BN]. ----
enum { EPI_F32 = 0, EPI_HILO = 1, EPI_V = 2 };

template <int BM, int BN, int WM, int WN, bool SPLIT, int EPI, bool TRI, int SPLITK = 1>
__global__ __launch_bounds__((BM / WM) * (BN / WN) * 64) void gemm2(
    const unsigned short* __restrict__ Ahi, const unsigned short* __restrict__ Alo,
    const unsigned short* __restrict__ Bhi, const unsigned short* __restrict__ Blo,
    long long sA, long long sB, int ldA, int ldB, int K,
    float* __restrict__ Cf, unsigned short* __restrict__ Chi, unsigned short* __restrict__ Clo,
    long long sC, int ldC, const float* __restrict__ bias, int gx, int gy) {
  constexpr int BK = 64;
  constexpr int WAVES = (BM / WM) * (BN / WN);
  constexpr int NS = SPLIT ? 2 : 1;
  constexpr int MI = WM / 16, NI = WN / 16;
  constexpr int NWN = BN / WN;
  constexpr int CA = BM / 8, CB = BN / 8;  // 1KB chunks per plane
  constexpr int TOT = NS * (CA + CB);
  constexpr bool COMPACT = TRI && (SPLITK > 1);
  __shared__ unsigned short lds[NS * (BM + BN) * BK];

  // bijective XCD-chunk swizzle (m204)
  int nwg = gridDim.x;
  int b = blockIdx.x;
  int q = nwg >> 3, r = nwg & 7, xcd = b & 7, pos = b >> 3;
  int wg = (xcd < r ? xcd * (q + 1) : r * (q + 1) + (xcd - r) * q) + pos;
  int bx, by, z, zc, tpi = 0, kbase = 0;
  if constexpr (TRI) {
    int tri = gy * (gy + 1) / 2;
    int perz = tri * SPLITK;
    z = wg / perz;
    int rem = wg - z * perz;
    int ks = rem / tri;
    tpi = rem - ks * tri;
    int tp = tpi;
    bx = 0;
    while (tp >= gy - bx) { tp -= gy - bx; ++bx; }
    by = bx + tp;
    kbase = ks * K;
    zc = z * SPLITK + ks;
  } else {
    by = wg % gy;
    int t2 = wg / gy;
    bx = t2 % gx;
    z = t2 / gx;
    zc = z;
  }

  const unsigned short* pA0 = Ahi + (size_t)z * sA + (size_t)bx * BM * ldA;
  const unsigned short* pB0 = Bhi + (size_t)z * sB + (size_t)by * BN * ldB;
  const unsigned short* pA1 = SPLIT ? Alo + (size_t)z * sA + (size_t)bx * BM * ldA : pA0;
  const unsigned short* pB1 = SPLIT ? Blo + (size_t)z * sB + (size_t)by * BN * ldB : pB0;

  int tid = threadIdx.x;
  int lane = tid & 63, wid = tid >> 6;
  int wr = wid / NWN, wc = wid % NWN;
  int lr = lane & 15, kh2 = lane >> 4;

  f32x4 acc[MI][NI] = {};

  for (int k0 = kbase; k0 < kbase + K; k0 += BK) {
    // stage: 8 rows x 64 elems per 1KB chunk; lane l -> row +(l>>3), phys slot l&7.
    // element for phys slot s at row r is logical slot s^(r&7) (read applies same XOR)
#pragma unroll
    for (int i = 0; i < TOT / WAVES; ++i) {
      int c = wid + i * WAVES;
      const unsigned short* srcb; int ldX, lofs, rb2;
      if (c < CA)            { srcb = pA0; ldX = ldA; lofs = c * 512;                  rb2 = c * 8; }
      else if (c < NS * CA)  { srcb = pA1; ldX = ldA; lofs = BM * BK + (c - CA) * 512; rb2 = (c - CA) * 8; }
      else if (c < NS * CA + CB) { int cc = c - NS * CA; srcb = pB0; ldX = ldB;
                                   lofs = NS * BM * BK + cc * 512;                     rb2 = cc * 8; }
      else                   { int cc = c - NS * CA - CB; srcb = pB1; ldX = ldB;
                               lofs = NS * BM * BK + BN * BK + cc * 512;               rb2 = cc * 8; }
      int row = rb2 + (lane >> 3);
      const unsigned short* src =
          srcb + (size_t)row * ldX + k0 + (((lane & 7) ^ (row & 7)) << 3);
      __builtin_amdgcn_global_load_lds(
          (const __attribute__((address_space(1))) void*)src,
          (__attribute__((address_space(3))) void*)(lds + lofs), 16, 0, 0);
    }
    __syncthreads();

#pragma unroll
    for (int kk = 0; kk < BK / 32; ++kk) {
      bf16x8 ah[MI], al[MI], bh[NI], bl[NI];
#pragma unroll
      for (int m = 0; m < MI; ++m) {
        int row = wr * WM + m * 16 + lr;
        int so = ((((kk << 2) | kh2) ^ (row & 7)) << 3);
        ah[m] = *reinterpret_cast<const bf16x8*>(&lds[row * BK + so]);
        if constexpr (SPLIT)
          al[m] = *reinterpret_cast<const bf16x8*>(&lds[BM * BK + row * BK + so]);
      }
#pragma unroll
      for (int n = 0; n < NI; ++n) {
        int row = wc * WN + n * 16 + lr;
        int so = ((((kk << 2) | kh2) ^ (row & 7)) << 3);
        bh[n] = *reinterpret_cast<const bf16x8*>(&lds[NS * BM * BK + row * BK + so]);
        if constexpr (SPLIT)
          bl[n] = *reinterpret_cast<const bf16x8*>(&lds[NS * BM * BK + BN * BK + row * BK + so]);
      }
#pragma unroll
      for (int m = 0; m < MI; ++m)
#pragma unroll
        for (int n = 0; n < NI; ++n) {
          acc[m][n] = __builtin_amdgcn_mfma_f32_16x16x32_bf16(ah[m], bh[n], acc[m][n], 0, 0, 0);
          if constexpr (SPLIT) {
            acc[m][n] = __builtin_amdgcn_mfma_f32_16x16x32_bf16(ah[m], bl[n], acc[m][n], 0, 0, 0);
            acc[m][n] = __builtin_amdgcn_mfma_f32_16x16x32_bf16(al[m], bh[n], acc[m][n], 0, 0, 0);
          }
        }
    }
    __syncthreads();
  }

  // epilogue: C/D layout col = lane&15, row = (lane>>4)*4 + reg
  int lg = lane >> 4;
#pragma unroll
  for (int m = 0; m < MI; ++m)
#pragma unroll
    for (int n = 0; n < NI; ++n) {
      int lcol = wc * WN + n * 16 + lr;
      float bcol = (EPI == EPI_V) ? bias[by * BN + lcol] : 0.f;
#pragma unroll
      for (int r4 = 0; r4 < 4; ++r4) {
        int lrow = wr * WM + m * 16 + lg * 4 + r4;
        float v = acc[m][n][r4];
        if constexpr (COMPACT) {
          size_t idx = (size_t)zc * sC + (size_t)tpi * (BM * BN) + (size_t)lrow * BN + lcol;
          Cf[idx] = v;
        } else {
          size_t idx = (size_t)zc * sC + (size_t)(bx * BM + lrow) * ldC + (by * BN + lcol);
          if constexpr (EPI == EPI_F32) {
            Cf[idx] = v;
          } else if constexpr (EPI == EPI_HILO) {
            unsigned short h = f2bf(v);
            Chi[idx] = h;
            Clo[idx] = f2bf(v - bf2f(h));
          } else {
            Chi[idx] = f2bf(v + bcol);
          }
        }
      }
    }
}

// ---- reduce Gram split-K partials + hi/lo split; upper 128-blocks of 512x512 ----
template <int KS>
__global__ void gram_reduce(const float* __restrict__ Gp,
                            unsigned short* __restrict__ Ghi, unsigned short* __restrict__ Glo) {
  int z = blockIdx.y;
  int tp = blockIdx.x;  // 0..NTRI-1
  int b2 = tp, bx = 0;
  while (b2 >= 4 - bx) { b2 -= 4 - bx; ++bx; }
  int by = bx + b2;
  int t = threadIdx.x;
  const float* base = Gp + ((size_t)z * KS * NTRI + tp) * (128 * 128);
  size_t gb = (size_t)z * CD * CD;
#pragma unroll
  for (int it = 0; it < 16; ++it) {
    int lrow = it * 8 + (t >> 5);
    int lc = (t & 31) * 4;
    f32x4 s = *reinterpret_cast<const f32x4*>(base + (size_t)lrow * 128 + lc);
#pragma unroll
    for (int ks = 1; ks < KS; ++ks)
      s += *reinterpret_cast<const f32x4*>(base + (size_t)ks * NTRI * 128 * 128 +
                                           (size_t)lrow * 128 + lc);
    u16x4 h, l;
#pragma unroll
    for (int i = 0; i < 4; ++i) {
      unsigned short hh = f2bf(s[i]);
      h[i] = hh; l[i] = f2bf(s[i] - bf2f(hh));
    }
    size_t o = gb + (size_t)(bx * 128 + lrow) * CD + by * 128 + lc;
    *reinterpret_cast<u16x4*>(Ghi + o) = h;
    *reinterpret_cast<u16x4*>(Glo + o) = l;
  }
}

// ---- mirror lower triangle of G from computed upper (128-block pairs bx<by) ----
__global__ void mirror_g(unsigned short* __restrict__ Ghi, unsigned short* __restrict__ Glo) {
  __shared__ unsigned short shh[64][72], shl[64][72];
  int z = blockIdx.y;
  int pidx = blockIdx.x >> 2, sub = blockIdx.x & 3;
  int bx = 0, tp = pidx;
  while (tp >= 3 - bx) { tp -= 3 - bx; ++bx; }
  int by = bx + 1 + tp;
  int ti = bx * 2 + (sub & 1), tj = by * 2 + (sub >> 1);
  int t = threadIdx.x;
  int rr = t >> 2, cg = (t & 3) * 16;
  size_t gbase = (size_t)z * CD * CD;
  size_t so = gbase + (size_t)(ti * 64 + rr) * CD + tj * 64 + cg;
  *reinterpret_cast<u16x8*>(&shh[rr][cg]) = *reinterpret_cast<const u16x8*>(Ghi + so);
  *reinterpret_cast<u16x8*>(&shh[rr][cg + 8]) = *reinterpret_cast<const u16x8*>(Ghi + so + 8);
  *reinterpret_cast<u16x8*>(&shl[rr][cg]) = *reinterpret_cast<const u16x8*>(Glo + so);
  *reinterpret_cast<u16x8*>(&shl[rr][cg + 8]) = *reinterpret_cast<const u16x8*>(Glo + so + 8);
  __syncthreads();
  u16x8 oh, ol;
  size_t dst = gbase + (size_t)(tj * 64 + rr) * CD + ti * 64 + cg;
#pragma unroll
  for (int half = 0; half < 2; ++half) {
#pragma unroll
    for (int i = 0; i < 8; ++i) {
      oh[i] = shh[cg + half * 8 + i][rr];
      ol[i] = shl[cg + half * 8 + i][rr];
    }
    *reinterpret_cast<u16x8*>(Ghi + dst + half * 8) = oh;
    *reinterpret_cast<u16x8*>(Glo + dst + half * 8) = ol;
  }
}

// ---- row softmax with rank-1 logit correction:
//      e[c][d] = E[c][d] + u'[c]*bk[d] + bq[c]*w[d]  ----
__global__ void softmax_rows(const float* __restrict__ E, unsigned short* __restrict__ attn,
                             const float* __restrict__ bq, const float* __restrict__ bk,
                             const float* __restrict__ uw) {
  int lane = threadIdx.x & 63, wid = threadIdx.x >> 6;
  size_t row = (size_t)blockIdx.x * 4 + wid;
  int z = (int)(row >> 9), c = (int)(row & 511);
  float uc = uw[(size_t)z * 2 * CD + c];
  float bqc = bq[c];
  const float* wp = uw + (size_t)z * 2 * CD + CD;
  const float* e = E + row * CD;
  int d0 = lane * 8;
  const float4* ep = reinterpret_cast<const float4*>(e + d0);
  float4 a = ep[0], b4 = ep[1];
  float4 k0 = *reinterpret_cast<const float4*>(bk + d0);
  float4 k1 = *reinterpret_cast<const float4*>(bk + d0 + 4);
  float4 w0 = *reinterpret_cast<const float4*>(wp + d0);
  float4 w1 = *reinterpret_cast<const float4*>(wp + d0 + 4);
  float v[8] = {a.x + uc * k0.x + bqc * w0.x, a.y + uc * k0.y + bqc * w0.y,
                a.z + uc * k0.z + bqc * w0.z, a.w + uc * k0.w + bqc * w0.w,
                b4.x + uc * k1.x + bqc * w1.x, b4.y + uc * k1.y + bqc * w1.y,
                b4.z + uc * k1.z + bqc * w1.z, b4.w + uc * k1.w + bqc * w1.w};
  float m = v[0];
#pragma unroll
  for (int i = 1; i < 8; ++i) m = fmaxf(m, v[i]);
  for (int o = 32; o > 0; o >>= 1) m = fmaxf(m, __shfl_xor(m, o));
  float s = 0.f;
#pragma unroll
  for (int i = 0; i < 8; ++i) { v[i] = __expf(v[i] - m); s += v[i]; }
  for (int o = 32; o > 0; o >>= 1) s += __shfl_xor(s, o);
  float rinv = 1.0f / s;
  u16x4 h0, h1;
#pragma unroll
  for (int i = 0; i < 4; ++i) { h0[i] = f2bf(v[i] * rinv); h1[i] = f2bf(v[4 + i] * rinv); }
  unsigned short* op = attn + row * CD + d0;
  *reinterpret_cast<u16x4*>(op) = h0;
  *reinterpret_cast<u16x4*>(op + 4) = h1;
}

extern "C" void kernel_launch(void* const* d_in, const int* in_sizes, int n_in,
                              void* d_out, int out_size, void* d_ws, size_t ws_size,
                              hipStream_t stream) {
  (void)in_sizes; (void)n_in; (void)out_size;
  const float* x  = (const float*)d_in[0];
  const float* Wq = (const float*)d_in[1];
  const float* bq = (const float*)d_in[2];
  const float* Wk = (const float*)d_in[3];
  const float* bk = (const float*)d_in[4];
  const float* Wv = (const float*)d_in[5];
  const float* bv = (const float*)d_in[6];
  float* out = (float*)d_out;

  char* base = (char*)d_ws;
  size_t off = 0;
  auto carve = [&](size_t bytes) -> char* {
    char* p = base + off;
    off += (bytes + 255) & ~(size_t)255;
    return p;
  };
  const size_t WB = (size_t)CD * CD * 2;
  unsigned short* Wqh = (unsigned short*)carve(WB);
  unsigned short* Wql = (unsigned short*)carve(WB);
  unsigned short* Wkh = (unsigned short*)carve(WB);
  unsigned short* Wkl = (unsigned short*)carve(WB);
  unsigned short* Wvh = (unsigned short*)carve(WB);

  const size_t CP = (size_t)CD * PD;
  const size_t GG = (size_t)CD * CD;
  const size_t EE = (size_t)CD * CD;
  const size_t per_batch = 3 * CP * 2 + 4 * GG * 2 + (size_t)CD * 64 * 4 + 2 * CD * 4 +
                           EE * 4 + EE * 2 + CP * 2 + 4096;
  size_t rem = (ws_size > off + 4096) ? (ws_size - off - 4096) : 0;
  int nb = (int)(rem / per_batch);
  if (nb < 1) nb = 1;
  if (nb > BD) nb = BD;

  unsigned short* xsh = (unsigned short*)carve((size_t)nb * CP * 2);
  unsigned short* xsl = (unsigned short*)carve((size_t)nb * CP * 2);
  unsigned short* xth = (unsigned short*)carve((size_t)nb * CP * 2);
  unsigned short* Ghi = (unsigned short*)carve((size_t)nb * GG * 2);
  unsigned short* Glo = (unsigned short*)carve((size_t)nb * GG * 2);
  unsigned short* Thi = (unsigned short*)carve((size_t)nb * GG * 2);
  unsigned short* Tlo = (unsigned short*)carve((size_t)nb * GG * 2);
  float*          r_part = (float*)carve((size_t)nb * CD * 64 * 4);
  float*          uw  = (float*)carve((size_t)nb * 2 * CD * 4);
  float*          E   = (float*)carve((size_t)nb * EE * 4);
  unsigned short* att = (unsigned short*)carve((size_t)nb * EE * 2);
  unsigned short* vT  = (unsigned short*)carve((size_t)nb * CP * 2);

  // Gram split-K partials alias the E/att/vT region (all written after gram_reduce):
  // need nb*GKS*NTRI*128*128*4 = nb*5.24MB <= nb*(EE*4 + EE*2 + CP*2) = nb*5.76MB
  float* Gpart = E;

  convert_w2<<<dim3((CD * CD + 255) / 256), 256, 0, stream>>>(
      Wq, Wk, Wv, Wqh, Wql, Wkh, Wkl, Wvh);

  for (int b0 = 0; b0 < BD; b0 += nb) {
    int cb = (BD - b0 < nb) ? (BD - b0) : nb;

    convert_x<<<dim3(PD / 64, CD / 64, cb), 256, 0, stream>>>(
        x + (size_t)b0 * CP, xsh, xsl, xth, r_part);

    uvw_kernel<<<dim3(cb, 8), 256, 0, stream>>>(r_part, Wq, bq, Wk, uw);

    // G partials = X X^T (upper triangle 128-blocks, split-K), fp32 compact out
    gemm2<128, 128, 64, 32, true, EPI_F32, true, GKS><<<NTRI * GKS * cb, 512, 0, stream>>>(
        xsh, xsl, xsh, xsl, (long long)CP, (long long)CP, PD, PD, PD / GKS,
        Gpart, nullptr, nullptr, (long long)NTRI * 128 * 128, 128, nullptr, 4, 4);

    gram_reduce<GKS><<<dim3(NTRI, cb), 256, 0, stream>>>(Gpart, Ghi, Glo);

    mirror_g<<<dim3(24, cb), 256, 0, stream>>>(Ghi, Glo);

    // T = Wq * G^T (G symmetric), split, hi/lo out [512][512]
    gemm2<64, 64, 32, 32, true, EPI_HILO, false><<<8 * 8 * cb, 256, 0, stream>>>(
        Wqh, Wql, Ghi, Glo, 0, (long long)GG, CD, CD, CD,
        nullptr, Thi, Tlo, (long long)GG, CD, nullptr, 8, 8);

    // E = T * Wk^T, split, fp32 out [512][512]
    gemm2<64, 64, 32, 32, true, EPI_F32, false><<<8 * 8 * cb, 256, 0, stream>>>(
        Thi, Tlo, Wkh, Wkl, (long long)GG, 0, CD, CD, CD,
        E, nullptr, nullptr, (long long)EE, CD, nullptr, 8, 8);

    softmax_rows<<<dim3(cb * CD / 4), 256, 0, stream>>>(E, att, bq, bk, uw);

    // vT[p][o] = xth * Wv^T + bv  [4096][512]
    gemm2<128, 128, 64, 64, false, EPI_V, false><<<32 * 4 * cb, 256, 0, stream>>>(
        xth, nullptr, Wvh, nullptr, (long long)CP, 0, CD, CD, CD,
        nullptr, vT, nullptr, (long long)CP, CD, bv, 32, 4);

    // out = attn * vT^T  [512][4096] fp32
    gemm2<128, 128, 64, 64, false, EPI_F32, false><<<4 * 32 * cb, 256, 0, stream>>>(
        att, nullptr, vT, nullptr, (long long)EE, (long long)CP, CD, CD, CD,
        out + (size_t)b0 * CP, nullptr, nullptr, (long long)CP, PD, nullptr, 4, 32);
  }
}

// Round 7
// 329.664 us; speedup vs baseline: 1.2144x; 1.0738x over previous
//
#include <hip/hip_runtime.h>
#include <hip/hip_bf16.h>

#define CD 512
#define PD 4096
#define BD 16
#define GKS 8      // Gram split-K factor (K chunks of 512)
#define NTRI 10    // upper-tri 128-blocks of 512x512

typedef __bf16 bf16x8 __attribute__((ext_vector_type(8)));
typedef float f32x4 __attribute__((ext_vector_type(4)));
typedef unsigned short u16x8 __attribute__((ext_vector_type(8)));
typedef unsigned short u16x4 __attribute__((ext_vector_type(4)));

__device__ __forceinline__ unsigned short f2bf(float f) {
  unsigned u = __builtin_bit_cast(unsigned, f);
  u += 0x7FFFu + ((u >> 16) & 1u);  // RNE
  return (unsigned short)(u >> 16);
}
__device__ __forceinline__ float bf2f(unsigned short h) {
  unsigned u = ((unsigned)h) << 16;
  return __builtin_bit_cast(float, u);
}

// ---- Wq, Wk -> hi/lo bf16 [512][512] ----
__global__ void convert_w2(const float* __restrict__ Wq, const float* __restrict__ Wk,
                           unsigned short* __restrict__ Wqh, unsigned short* __restrict__ Wql,
                           unsigned short* __restrict__ Wkh, unsigned short* __restrict__ Wkl) {
  int i = blockIdx.x * 256 + threadIdx.x;
  if (i >= CD * CD) return;
  float q = Wq[i]; unsigned short qh = f2bf(q);
  Wqh[i] = qh; Wql[i] = f2bf(q - bf2f(qh));
  float k = Wk[i]; unsigned short kh = f2bf(k);
  Wkh[i] = kh; Wkl[i] = f2bf(k - bf2f(kh));
}

// ---- Wvt[i][d] = bf16(Wv[d][i]) via LDS tile transpose ----
__global__ void transpose_wv(const float* __restrict__ Wv, unsigned short* __restrict__ Wvt) {
  __shared__ float tile[64][65];
  int o0 = blockIdx.x * 64, j0 = blockIdx.y * 64;
  int t = threadIdx.x, r = t >> 2, g = t & 3;
  const float* src = Wv + (size_t)(o0 + r) * CD + j0 + g * 16;
#pragma unroll
  for (int i = 0; i < 16; ++i) tile[r][g * 16 + i] = src[i];
  __syncthreads();
  u16x8 th[2];
#pragma unroll
  for (int i = 0; i < 16; ++i) th[i >> 3][i & 7] = f2bf(tile[g * 16 + i][r]);
  unsigned short* dst = Wvt + (size_t)(j0 + r) * CD + o0 + g * 16;
  *reinterpret_cast<u16x8*>(dst) = th[0];
  *reinterpret_cast<u16x8*>(dst + 8) = th[1];
}

// ---- x[b][512][4096] fp32 -> xs hi/lo bf16 (straight) + xth [b][4096][512]
//      + per-tile row-sum partials. Single load pass, 16B stores. ----
__global__ void convert_x(const float* __restrict__ x, unsigned short* __restrict__ xsh,
                          unsigned short* __restrict__ xsl, unsigned short* __restrict__ xth,
                          float* __restrict__ r_part) {
  __shared__ float tile[64][65];
  int z = blockIdx.z;
  int c0 = blockIdx.y * 64, p0 = blockIdx.x * 64;
  int t = threadIdx.x, r = t >> 2, g = t & 3;
  const float* src = x + (size_t)z * CD * PD + (size_t)(c0 + r) * PD + p0 + g * 16;
  f32x4 v4[4];
  float s = 0.f;
#pragma unroll
  for (int j = 0; j < 4; ++j) {
    v4[j] = *reinterpret_cast<const f32x4*>(src + j * 4);
#pragma unroll
    for (int i = 0; i < 4; ++i) {
      tile[r][g * 16 + j * 4 + i] = v4[j][i];
      s += v4[j][i];
    }
  }
  s += __shfl_xor(s, 1);
  s += __shfl_xor(s, 2);
  if (g == 0) r_part[((size_t)z * CD + c0 + r) * 64 + (p0 >> 6)] = s;
  // straight hi/lo from registers
  u16x8 h[2], l[2];
#pragma unroll
  for (int j = 0; j < 4; ++j)
#pragma unroll
    for (int i = 0; i < 4; ++i) {
      int e = j * 4 + i;
      float f = v4[j][i];
      unsigned short hh = f2bf(f);
      h[e >> 3][e & 7] = hh;
      l[e >> 3][e & 7] = f2bf(f - bf2f(hh));
    }
  size_t so = (size_t)z * CD * PD + (size_t)(c0 + r) * PD + p0 + g * 16;
  *reinterpret_cast<u16x8*>(xsh + so) = h[0];
  *reinterpret_cast<u16x8*>(xsh + so + 8) = h[1];
  *reinterpret_cast<u16x8*>(xsl + so) = l[0];
  *reinterpret_cast<u16x8*>(xsl + so + 8) = l[1];
  __syncthreads();
  // transposed hi: thread covers p-row r, channels g*16..+15
  u16x8 th[2];
#pragma unroll
  for (int i = 0; i < 16; ++i) th[i >> 3][i & 7] = f2bf(tile[g * 16 + i][r]);
  size_t to = (size_t)z * PD * CD + (size_t)(p0 + r) * CD + c0 + g * 16;
  *reinterpret_cast<u16x8*>(xth + to) = th[0];
  *reinterpret_cast<u16x8*>(xth + to + 8) = th[1];
}

// ---- r = sum_p x; u' = Wq r + P bq; w = Wk r  (fp32, coalesced wave-per-row) ----
__global__ void uvw_kernel(const float* __restrict__ r_part, const float* __restrict__ Wq,
                           const float* __restrict__ bq, const float* __restrict__ Wk,
                           float* __restrict__ uw) {
  __shared__ float rl[CD];
  int z = blockIdx.x, rg = blockIdx.y;
  int t = threadIdx.x;
  for (int c = t; c < CD; c += 256) {
    const float* rp = r_part + ((size_t)z * CD + c) * 64;
    f32x4 s4 = *reinterpret_cast<const f32x4*>(rp);
#pragma unroll
    for (int pb = 4; pb < 64; pb += 4) s4 += *reinterpret_cast<const f32x4*>(rp + pb);
    rl[c] = s4[0] + s4[1] + s4[2] + s4[3];
  }
  __syncthreads();
  int lane = t & 63, w = t >> 6;
#pragma unroll
  for (int rr = 0; rr < 16; ++rr) {
    int c = rg * 64 + w * 16 + rr;
    const float* wq = Wq + (size_t)c * CD;
    const float* wk = Wk + (size_t)c * CD;
    float du = 0.f, dw = 0.f;
#pragma unroll
    for (int j = 0; j < 8; ++j) {
      float rv = rl[lane + 64 * j];
      du += wq[lane + 64 * j] * rv;
      dw += wk[lane + 64 * j] * rv;
    }
#pragma unroll
    for (int o = 32; o > 0; o >>= 1) {
      du += __shfl_xor(du, o);
      dw += __shfl_xor(dw, o);
    }
    if (lane == 0) {
      uw[(size_t)z * 2 * CD + c] = du + (float)PD * bq[c];
      uw[(size_t)z * 2 * CD + CD + c] = dw;
    }
  }
}

// ---- generic C[M][N] = sum_k A[M][k]*B[N][k], bf16 MFMA 16x16x32, BK=64,
//      global_load_lds staging with XOR slot swizzle, 1D XCD-chunked grid. ----
enum { EPI_F32 = 0, EPI_HILO = 1, EPI_BF16 = 2, EPI_ROWB = 3 };

template <int BM, int BN, int WM, int WN, bool SPLIT, int EPI, bool TRI, int SPLITK = 1>
__global__ __launch_bounds__((BM / WM) * (BN / WN) * 64) void gemm2(
    const unsigned short* __restrict__ Ahi, const unsigned short* __restrict__ Alo,
    const unsigned short* __restrict__ Bhi, const unsigned short* __restrict__ Blo,
    long long sA, long long sB, int ldA, int ldB, int K,
    float* __restrict__ Cf, unsigned short* __restrict__ Chi, unsigned short* __restrict__ Clo,
    long long sC, int ldC, const float* __restrict__ bias, int gx, int gy) {
  constexpr int BK = 64;
  constexpr int WAVES = (BM / WM) * (BN / WN);
  constexpr int NS = SPLIT ? 2 : 1;
  constexpr int MI = WM / 16, NI = WN / 16;
  constexpr int NWN = BN / WN;
  constexpr int CA = BM / 8, CB = BN / 8;  // 1KB chunks per plane
  constexpr int TOT = NS * (CA + CB);
  constexpr bool COMPACT = TRI && (SPLITK > 1);
  __shared__ unsigned short lds[NS * (BM + BN) * BK];

  // bijective XCD-chunk swizzle (m204)
  int nwg = gridDim.x;
  int b = blockIdx.x;
  int q = nwg >> 3, r = nwg & 7, xcd = b & 7, pos = b >> 3;
  int wg = (xcd < r ? xcd * (q + 1) : r * (q + 1) + (xcd - r) * q) + pos;
  int bx, by, z, zc, tpi = 0, kbase = 0;
  if constexpr (TRI) {
    int tri = gy * (gy + 1) / 2;
    int perz = tri * SPLITK;
    z = wg / perz;
    int rem = wg - z * perz;
    int ks = rem / tri;
    tpi = rem - ks * tri;
    int tp = tpi;
    bx = 0;
    while (tp >= gy - bx) { tp -= gy - bx; ++bx; }
    by = bx + tp;
    kbase = ks * K;
    zc = z * SPLITK + ks;
  } else {
    by = wg % gy;
    int t2 = wg / gy;
    bx = t2 % gx;
    z = t2 / gx;
    zc = z;
  }

  const unsigned short* pA0 = Ahi + (size_t)z * sA + (size_t)bx * BM * ldA;
  const unsigned short* pB0 = Bhi + (size_t)z * sB + (size_t)by * BN * ldB;
  const unsigned short* pA1 = SPLIT ? Alo + (size_t)z * sA + (size_t)bx * BM * ldA : pA0;
  const unsigned short* pB1 = SPLIT ? Blo + (size_t)z * sB + (size_t)by * BN * ldB : pB0;

  int tid = threadIdx.x;
  int lane = tid & 63, wid = tid >> 6;
  int wr = wid / NWN, wc = wid % NWN;
  int lr = lane & 15, kh2 = lane >> 4;

  f32x4 acc[MI][NI] = {};

  for (int k0 = kbase; k0 < kbase + K; k0 += BK) {
#pragma unroll
    for (int i = 0; i < TOT / WAVES; ++i) {
      int c = wid + i * WAVES;
      const unsigned short* srcb; int ldX, lofs, rb2;
      if (c < CA)            { srcb = pA0; ldX = ldA; lofs = c * 512;                  rb2 = c * 8; }
      else if (c < NS * CA)  { srcb = pA1; ldX = ldA; lofs = BM * BK + (c - CA) * 512; rb2 = (c - CA) * 8; }
      else if (c < NS * CA + CB) { int cc = c - NS * CA; srcb = pB0; ldX = ldB;
                                   lofs = NS * BM * BK + cc * 512;                     rb2 = cc * 8; }
      else                   { int cc = c - NS * CA - CB; srcb = pB1; ldX = ldB;
                               lofs = NS * BM * BK + BN * BK + cc * 512;               rb2 = cc * 8; }
      int row = rb2 + (lane >> 3);
      const unsigned short* src =
          srcb + (size_t)row * ldX + k0 + (((lane & 7) ^ (row & 7)) << 3);
      __builtin_amdgcn_global_load_lds(
          (const __attribute__((address_space(1))) void*)src,
          (__attribute__((address_space(3))) void*)(lds + lofs), 16, 0, 0);
    }
    __syncthreads();

#pragma unroll
    for (int kk = 0; kk < BK / 32; ++kk) {
      bf16x8 ah[MI], al[MI], bh[NI], bl[NI];
#pragma unroll
      for (int m = 0; m < MI; ++m) {
        int row = wr * WM + m * 16 + lr;
        int so = ((((kk << 2) | kh2) ^ (row & 7)) << 3);
        ah[m] = *reinterpret_cast<const bf16x8*>(&lds[row * BK + so]);
        if constexpr (SPLIT)
          al[m] = *reinterpret_cast<const bf16x8*>(&lds[BM * BK + row * BK + so]);
      }
#pragma unroll
      for (int n = 0; n < NI; ++n) {
        int row = wc * WN + n * 16 + lr;
        int so = ((((kk << 2) | kh2) ^ (row & 7)) << 3);
        bh[n] = *reinterpret_cast<const bf16x8*>(&lds[NS * BM * BK + row * BK + so]);
        if constexpr (SPLIT)
          bl[n] = *reinterpret_cast<const bf16x8*>(&lds[NS * BM * BK + BN * BK + row * BK + so]);
      }
#pragma unroll
      for (int m = 0; m < MI; ++m)
#pragma unroll
        for (int n = 0; n < NI; ++n) {
          acc[m][n] = __builtin_amdgcn_mfma_f32_16x16x32_bf16(ah[m], bh[n], acc[m][n], 0, 0, 0);
          if constexpr (SPLIT) {
            acc[m][n] = __builtin_amdgcn_mfma_f32_16x16x32_bf16(ah[m], bl[n], acc[m][n], 0, 0, 0);
            acc[m][n] = __builtin_amdgcn_mfma_f32_16x16x32_bf16(al[m], bh[n], acc[m][n], 0, 0, 0);
          }
        }
    }
    __syncthreads();
  }

  // epilogue: C/D layout col = lane&15, row = (lane>>4)*4 + reg
  int lg = lane >> 4;
#pragma unroll
  for (int m = 0; m < MI; ++m)
#pragma unroll
    for (int n = 0; n < NI; ++n) {
      int lcol = wc * WN + n * 16 + lr;
#pragma unroll
      for (int r4 = 0; r4 < 4; ++r4) {
        int lrow = wr * WM + m * 16 + lg * 4 + r4;
        float v = acc[m][n][r4];
        if constexpr (COMPACT) {
          size_t idx = (size_t)zc * sC + (size_t)tpi * (BM * BN) + (size_t)lrow * BN + lcol;
          Cf[idx] = v;
        } else {
          size_t idx = (size_t)zc * sC + (size_t)(bx * BM + lrow) * ldC + (by * BN + lcol);
          if constexpr (EPI == EPI_F32) {
            Cf[idx] = v;
          } else if constexpr (EPI == EPI_ROWB) {
            Cf[idx] = v + bias[(size_t)zc * CD + bx * BM + lrow];
          } else if constexpr (EPI == EPI_HILO) {
            unsigned short h = f2bf(v);
            Chi[idx] = h;
            Clo[idx] = f2bf(v - bf2f(h));
          } else {  // EPI_BF16
            Chi[idx] = f2bf(v);
          }
        }
      }
    }
}

// ---- reduce Gram split-K partials + hi/lo split; upper 128-blocks of 512x512 ----
template <int KS>
__global__ void gram_reduce(const float* __restrict__ Gp,
                            unsigned short* __restrict__ Ghi, unsigned short* __restrict__ Glo) {
  int z = blockIdx.y;
  int tp = blockIdx.x;  // 0..NTRI-1
  int b2 = tp, bx = 0;
  while (b2 >= 4 - bx) { b2 -= 4 - bx; ++bx; }
  int by = bx + b2;
  int t = threadIdx.x;
  const float* base = Gp + ((size_t)z * KS * NTRI + tp) * (128 * 128);
  size_t gb = (size_t)z * CD * CD;
#pragma unroll
  for (int it = 0; it < 16; ++it) {
    int lrow = it * 8 + (t >> 5);
    int lc = (t & 31) * 4;
    f32x4 s = *reinterpret_cast<const f32x4*>(base + (size_t)lrow * 128 + lc);
#pragma unroll
    for (int ks = 1; ks < KS; ++ks)
      s += *reinterpret_cast<const f32x4*>(base + (size_t)ks * NTRI * 128 * 128 +
                                           (size_t)lrow * 128 + lc);
    u16x4 h, l;
#pragma unroll
    for (int i = 0; i < 4; ++i) {
      unsigned short hh = f2bf(s[i]);
      h[i] = hh; l[i] = f2bf(s[i] - bf2f(hh));
    }
    size_t o = gb + (size_t)(bx * 128 + lrow) * CD + by * 128 + lc;
    *reinterpret_cast<u16x4*>(Ghi + o) = h;
    *reinterpret_cast<u16x4*>(Glo + o) = l;
  }
}

// ---- mirror lower triangle of G from computed upper (128-block pairs bx<by) ----
__global__ void mirror_g(unsigned short* __restrict__ Ghi, unsigned short* __restrict__ Glo) {
  __shared__ unsigned short shh[64][72], shl[64][72];
  int z = blockIdx.y;
  int pidx = blockIdx.x >> 2, sub = blockIdx.x & 3;
  int bx = 0, tp = pidx;
  while (tp >= 3 - bx) { tp -= 3 - bx; ++bx; }
  int by = bx + 1 + tp;
  int ti = bx * 2 + (sub & 1), tj = by * 2 + (sub >> 1);
  int t = threadIdx.x;
  int rr = t >> 2, cg = (t & 3) * 16;
  size_t gbase = (size_t)z * CD * CD;
  size_t so = gbase + (size_t)(ti * 64 + rr) * CD + tj * 64 + cg;
  *reinterpret_cast<u16x8*>(&shh[rr][cg]) = *reinterpret_cast<const u16x8*>(Ghi + so);
  *reinterpret_cast<u16x8*>(&shh[rr][cg + 8]) = *reinterpret_cast<const u16x8*>(Ghi + so + 8);
  *reinterpret_cast<u16x8*>(&shl[rr][cg]) = *reinterpret_cast<const u16x8*>(Glo + so);
  *reinterpret_cast<u16x8*>(&shl[rr][cg + 8]) = *reinterpret_cast<const u16x8*>(Glo + so + 8);
  __syncthreads();
  u16x8 oh, ol;
  size_t dst = gbase + (size_t)(tj * 64 + rr) * CD + ti * 64 + cg;
#pragma unroll
  for (int half = 0; half < 2; ++half) {
#pragma unroll
    for (int i = 0; i < 8; ++i) {
      oh[i] = shh[cg + half * 8 + i][rr];
      ol[i] = shl[cg + half * 8 + i][rr];
    }
    *reinterpret_cast<u16x8*>(Ghi + dst + half * 8) = oh;
    *reinterpret_cast<u16x8*>(Glo + dst + half * 8) = ol;
  }
}

// ---- row softmax with rank-1 logit correction + sv = sum_d att*bv ----
__global__ void softmax_rows(const float* __restrict__ E, unsigned short* __restrict__ attn,
                             const float* __restrict__ bq, const float* __restrict__ bk,
                             const float* __restrict__ uw, const float* __restrict__ bv,
                             float* __restrict__ sv) {
  int lane = threadIdx.x & 63, wid = threadIdx.x >> 6;
  size_t row = (size_t)blockIdx.x * 4 + wid;
  int z = (int)(row >> 9), c = (int)(row & 511);
  float uc = uw[(size_t)z * 2 * CD + c];
  float bqc = bq[c];
  const float* wp = uw + (size_t)z * 2 * CD + CD;
  const float* e = E + row * CD;
  int d0 = lane * 8;
  const float4* ep = reinterpret_cast<const float4*>(e + d0);
  float4 a = ep[0], b4 = ep[1];
  float4 k0 = *reinterpret_cast<const float4*>(bk + d0);
  float4 k1 = *reinterpret_cast<const float4*>(bk + d0 + 4);
  float4 w0 = *reinterpret_cast<const float4*>(wp + d0);
  float4 w1 = *reinterpret_cast<const float4*>(wp + d0 + 4);
  float v[8] = {a.x + uc * k0.x + bqc * w0.x, a.y + uc * k0.y + bqc * w0.y,
                a.z + uc * k0.z + bqc * w0.z, a.w + uc * k0.w + bqc * w0.w,
                b4.x + uc * k1.x + bqc * w1.x, b4.y + uc * k1.y + bqc * w1.y,
                b4.z + uc * k1.z + bqc * w1.z, b4.w + uc * k1.w + bqc * w1.w};
  float m = v[0];
#pragma unroll
  for (int i = 1; i < 8; ++i) m = fmaxf(m, v[i]);
  for (int o = 32; o > 0; o >>= 1) m = fmaxf(m, __shfl_xor(m, o));
  float s = 0.f;
#pragma unroll
  for (int i = 0; i < 8; ++i) { v[i] = __expf(v[i] - m); s += v[i]; }
  for (int o = 32; o > 0; o >>= 1) s += __shfl_xor(s, o);
  float rinv = 1.0f / s;
  float4 bv0 = *reinterpret_cast<const float4*>(bv + d0);
  float4 bv1 = *reinterpret_cast<const float4*>(bv + d0 + 4);
  u16x4 h0, h1;
  float svp = 0.f;
#pragma unroll
  for (int i = 0; i < 4; ++i) {
    h0[i] = f2bf(v[i] * rinv);
    h1[i] = f2bf(v[4 + i] * rinv);
    svp += bf2f(h0[i]) * (&bv0.x)[i] + bf2f(h1[i]) * (&bv1.x)[i];
  }
  for (int o = 32; o > 0; o >>= 1) svp += __shfl_xor(svp, o);
  if (lane == 0) sv[row] = svp;
  unsigned short* op = attn + row * CD + d0;
  *reinterpret_cast<u16x4*>(op) = h0;
  *reinterpret_cast<u16x4*>(op + 4) = h1;
}

extern "C" void kernel_launch(void* const* d_in, const int* in_sizes, int n_in,
                              void* d_out, int out_size, void* d_ws, size_t ws_size,
                              hipStream_t stream) {
  (void)in_sizes; (void)n_in; (void)out_size;
  const float* x  = (const float*)d_in[0];
  const float* Wq = (const float*)d_in[1];
  const float* bq = (const float*)d_in[2];
  const float* Wk = (const float*)d_in[3];
  const float* bk = (const float*)d_in[4];
  const float* Wv = (const float*)d_in[5];
  const float* bv = (const float*)d_in[6];
  float* out = (float*)d_out;

  char* base = (char*)d_ws;
  size_t off = 0;
  auto carve = [&](size_t bytes) -> char* {
    char* p = base + off;
    off += (bytes + 255) & ~(size_t)255;
    return p;
  };
  const size_t WB = (size_t)CD * CD * 2;
  unsigned short* Wqh = (unsigned short*)carve(WB);
  unsigned short* Wql = (unsigned short*)carve(WB);
  unsigned short* Wkh = (unsigned short*)carve(WB);
  unsigned short* Wkl = (unsigned short*)carve(WB);
  unsigned short* Wvt = (unsigned short*)carve(WB);

  const size_t CP = (size_t)CD * PD;
  const size_t GG = (size_t)CD * CD;
  const size_t EE = (size_t)CD * CD;
  const size_t PERZC = (size_t)NTRI * 128 * 128;  // compact partial stride per zc
  const size_t GPB = (size_t)GKS * PERZC;         // Gram partial elems/batch
  const size_t per_batch = 3 * CP * 2 + 4 * GG * 2 + (size_t)CD * 64 * 4 + 2 * CD * 4 +
                           (size_t)CD * 4 + EE * 4 + EE * 2 + GPB * 4 + 8192;
  size_t rem = (ws_size > off + 4096) ? (ws_size - off - 4096) : 0;
  int nb = (int)(rem / per_batch);
  if (nb < 1) nb = 1;
  if (nb > BD) nb = BD;

  unsigned short* xsh = (unsigned short*)carve((size_t)nb * CP * 2);
  unsigned short* xsl = (unsigned short*)carve((size_t)nb * CP * 2);
  unsigned short* xth = (unsigned short*)carve((size_t)nb * CP * 2);
  unsigned short* Ghi = (unsigned short*)carve((size_t)nb * GG * 2);
  unsigned short* Glo = (unsigned short*)carve((size_t)nb * GG * 2);
  unsigned short* Thi = (unsigned short*)carve((size_t)nb * GG * 2);  // reused as Mb
  unsigned short* Tlo = (unsigned short*)carve((size_t)nb * GG * 2);
  float*          r_part = (float*)carve((size_t)nb * CD * 64 * 4);
  float*          uw  = (float*)carve((size_t)nb * 2 * CD * 4);
  float*          sv  = (float*)carve((size_t)nb * CD * 4);
  float*          E   = (float*)carve((size_t)nb * EE * 4);
  unsigned short* att = (unsigned short*)carve((size_t)nb * EE * 2);
  float*          Gpart = (float*)carve((size_t)nb * GPB * 4);

  convert_w2<<<dim3((CD * CD + 255) / 256), 256, 0, stream>>>(Wq, Wk, Wqh, Wql, Wkh, Wkl);
  transpose_wv<<<dim3(8, 8), 256, 0, stream>>>(Wv, Wvt);

  for (int b0 = 0; b0 < BD; b0 += nb) {
    int cb = (BD - b0 < nb) ? (BD - b0) : nb;

    convert_x<<<dim3(PD / 64, CD / 64, cb), 256, 0, stream>>>(
        x + (size_t)b0 * CP, xsh, xsl, xth, r_part);

    uvw_kernel<<<dim3(cb, 8), 256, 0, stream>>>(r_part, Wq, bq, Wk, uw);

    // G partials = X X^T (upper triangle 128-blocks, split-K), fp32 compact out.
    // sC is the per-zc stride (PERZC), matching gram_reduce's [z][ks][tri] layout.
    gemm2<128, 128, 64, 32, true, EPI_F32, true, GKS><<<NTRI * GKS * cb, 512, 0, stream>>>(
        xsh, xsl, xsh, xsl, (long long)CP, (long long)CP, PD, PD, PD / GKS,
        Gpart, nullptr, nullptr, (long long)PERZC, 128, nullptr, 4, 4);

    gram_reduce<GKS><<<dim3(NTRI, cb), 256, 0, stream>>>(Gpart, Ghi, Glo);

    mirror_g<<<dim3(24, cb), 256, 0, stream>>>(Ghi, Glo);

    // T = Wq * G^T (G symmetric), split, hi/lo out [512][512]
    gemm2<64, 64, 32, 32, true, EPI_HILO, false><<<8 * 8 * cb, 256, 0, stream>>>(
        Wqh, Wql, Ghi, Glo, 0, (long long)GG, CD, CD, CD,
        nullptr, Thi, Tlo, (long long)GG, CD, nullptr, 8, 8);

    // E = T * Wk^T, split, fp32 out [512][512]
    gemm2<64, 64, 32, 32, true, EPI_F32, false><<<8 * 8 * cb, 256, 0, stream>>>(
        Thi, Tlo, Wkh, Wkl, (long long)GG, 0, CD, CD, CD,
        E, nullptr, nullptr, (long long)EE, CD, nullptr, 8, 8);

    softmax_rows<<<dim3(cb * CD / 4), 256, 0, stream>>>(E, att, bq, bk, uw, bv, sv);

    // M = att * Wvt^T  [512][512] bf16 (reuse Thi as Mb; T no longer needed)
    gemm2<64, 64, 32, 32, false, EPI_BF16, false><<<8 * 8 * cb, 256, 0, stream>>>(
        att, nullptr, Wvt, nullptr, (long long)EE, 0, CD, CD, CD,
        nullptr, Thi, nullptr, (long long)GG, CD, nullptr, 8, 8);

    // out = M * xth^T + sv[row]  [512][4096] fp32
    gemm2<128, 128, 64, 64, false, EPI_ROWB, false><<<4 * 32 * cb, 256, 0, stream>>>(
        Thi, nullptr, xth, nullptr, (long long)GG, (long long)CP, CD, CD, CD,
        out + (size_t)b0 * CP, nullptr, nullptr, (long long)CP, PD, sv, 4, 32);
  }
}